// Round 1
// baseline (483.412 us; speedup 1.0000x reference)
//
#include <hip/hip_runtime.h>
#include <math.h>

#define NN 50000
#define RR 8
#define EE 100000
#define BB 16384
#define DD 128
#define OO 128
#define CAP 16
#define OVF_CAP 32768

// ---------------- bucket build: group edges by (relation, row-node) ----------------
__global__ __launch_bounds__(256) void fill_buckets(
    const int* __restrict__ rows, int* __restrict__ count,
    int* __restrict__ buckets, int* __restrict__ ovf_cnt, int* __restrict__ ovf_list)
{
    int t = blockIdx.x * 256 + threadIdx.x;
    if (t >= RR * EE) return;
    int r = t / EE;
    int e = t - r * EE;
    int row = rows[t];
    int key = r * NN + row;
    int pos = atomicAdd(&count[key], 1);
    if (pos < CAP) {
        buckets[key * CAP + pos] = e;
    } else {
        int o = atomicAdd(ovf_cnt, 1);
        if (o < OVF_CAP) ovf_list[o] = (r << 20) | e;   // e < 2^17, r < 8
    }
}

// ---------------- fp32 tile GEMM: C[M x 128] = A[M x 128] @ B[128 x 128] ----------------
// block: 256 threads, 64 rows x 128 cols per block, BK=64, micro-tile 8x4.
// DUAL: A rows [0,Msplit) from A1, [Msplit,M) from A2 (for concat(head_e, tail_e)).
template<bool DUAL>
__global__ __launch_bounds__(256) void gemm128(
    const float* __restrict__ A1, const float* __restrict__ A2, int Msplit,
    const float* __restrict__ Bm, float* __restrict__ C, int M)
{
    __shared__ float As[64][68];   // As[k][row], pitch 68 keeps float4 alignment
    __shared__ float Bs[64][128];
    const int tid = threadIdx.x;
    const int m0 = blockIdx.x * 64;
    const int c0 = (tid & 31) * 4;
    const int r0 = (tid >> 5) * 8;
    float acc[8][4] = {};

    for (int k0 = 0; k0 < DD; k0 += 64) {
        // A tile: 64 rows x 64 k, transposed into LDS
        #pragma unroll
        for (int i = 0; i < 4; i++) {
            int row = (tid >> 4) + 16 * i;
            int grow = m0 + row;
            if (grow >= M) grow = M - 1;          // clamp (guarded on store)
            const float* Ap = A1;
            int gr = grow;
            if (DUAL && grow >= Msplit) { Ap = A2; gr = grow - Msplit; }
            int kk = (tid & 15) * 4;
            float4 v = *reinterpret_cast<const float4*>(&Ap[(size_t)gr * DD + k0 + kk]);
            As[kk + 0][row] = v.x;
            As[kk + 1][row] = v.y;
            As[kk + 2][row] = v.z;
            As[kk + 3][row] = v.w;
        }
        // B tile: 64 k x 128 n
        #pragma unroll
        for (int i = 0; i < 8; i++) {
            int idx = tid + 256 * i;
            int kk = idx >> 5;
            int nn = (idx & 31) * 4;
            *reinterpret_cast<float4*>(&Bs[kk][nn]) =
                *reinterpret_cast<const float4*>(&Bm[(size_t)(k0 + kk) * OO + nn]);
        }
        __syncthreads();
        #pragma unroll
        for (int k = 0; k < 64; k++) {
            float4 alo = *reinterpret_cast<const float4*>(&As[k][r0]);
            float4 ahi = *reinterpret_cast<const float4*>(&As[k][r0 + 4]);
            float4 b   = *reinterpret_cast<const float4*>(&Bs[k][c0]);
            float av[8] = {alo.x, alo.y, alo.z, alo.w, ahi.x, ahi.y, ahi.z, ahi.w};
            #pragma unroll
            for (int i = 0; i < 8; i++) {
                acc[i][0] = fmaf(av[i], b.x, acc[i][0]);
                acc[i][1] = fmaf(av[i], b.y, acc[i][1]);
                acc[i][2] = fmaf(av[i], b.z, acc[i][2]);
                acc[i][3] = fmaf(av[i], b.w, acc[i][3]);
            }
        }
        __syncthreads();
    }
    #pragma unroll
    for (int i = 0; i < 8; i++) {
        int grow = m0 + r0 + i;
        if (grow < M) {
            float4 v = make_float4(acc[i][0], acc[i][1], acc[i][2], acc[i][3]);
            *reinterpret_cast<float4*>(&C[(size_t)grow * OO + c0]) = v;
        }
    }
}

// ---------------- per-relation gather: out[b,:] += sum_{e in bucket(r, idx[b])} v * T[col,:] ----------------
__global__ __launch_bounds__(256) void gather_accum(
    const int* __restrict__ head_idx, const int* __restrict__ tail_idx,
    const int* __restrict__ count, const int* __restrict__ buckets,
    const int* __restrict__ cols, const float* __restrict__ vals,
    const float* __restrict__ T, float* __restrict__ out, int r)
{
    int t = blockIdx.x * 256 + threadIdx.x;
    int b = t >> 5;                 // 32 threads per batch row (float4 each)
    if (b >= 2 * BB) return;
    int d4 = (t & 31) * 4;
    int n = (b < BB) ? head_idx[b] : tail_idx[b - BB];
    int key = r * NN + n;
    int cnt = count[key];
    if (cnt > CAP) cnt = CAP;
    const int* bk = &buckets[(size_t)key * CAP];
    float4 acc = make_float4(0.f, 0.f, 0.f, 0.f);
    for (int j = 0; j < cnt; j++) {
        int e = bk[j];
        float v  = vals[r * EE + e];
        int col  = cols[r * EE + e];
        float4 tv = *reinterpret_cast<const float4*>(&T[(size_t)col * OO + d4]);
        acc.x = fmaf(v, tv.x, acc.x);
        acc.y = fmaf(v, tv.y, acc.y);
        acc.z = fmaf(v, tv.z, acc.z);
        acc.w = fmaf(v, tv.w, acc.w);
    }
    float4* op = reinterpret_cast<float4*>(&out[(size_t)b * OO + d4]);
    float4 cur = *op;
    cur.x += acc.x; cur.y += acc.y; cur.z += acc.z; cur.w += acc.w;
    *op = cur;
}

// ---------------- overflow fallback (no-op in practice, guarantees correctness) ----------------
__global__ __launch_bounds__(256) void ovf_fix(
    const int* __restrict__ ovf_cnt, const int* __restrict__ ovf_list,
    const int* __restrict__ rows, const int* __restrict__ cols, const float* __restrict__ vals,
    const int* __restrict__ head_idx, const int* __restrict__ tail_idx,
    const float* __restrict__ T, float* __restrict__ out, int r)
{
    int novf = *ovf_cnt;
    if (novf > OVF_CAP) novf = OVF_CAP;
    for (int i = blockIdx.x; i < novf; i += gridDim.x) {
        int pack = ovf_list[i];
        if ((pack >> 20) != r) continue;
        int e = pack & 0xFFFFF;
        int row = rows[r * EE + e];
        int col = cols[r * EE + e];
        float v = vals[r * EE + e];
        for (int b = threadIdx.x; b < 2 * BB; b += 256) {
            int n = (b < BB) ? head_idx[b] : tail_idx[b - BB];
            if (n == row) {
                for (int d = 0; d < OO; d++)
                    atomicAdd(&out[(size_t)b * OO + d], v * T[(size_t)col * OO + d]);
            }
        }
    }
}

// ---------------- epilogue: in-place sigmoid ----------------
__global__ __launch_bounds__(256) void sigmoid_inplace(float* __restrict__ out)
{
    int t = blockIdx.x * 256 + threadIdx.x;      // 2*BB*OO/4 float4s
    float4* p = reinterpret_cast<float4*>(out) + t;
    float4 v = *p;
    v.x = 1.f / (1.f + __expf(-v.x));
    v.y = 1.f / (1.f + __expf(-v.y));
    v.z = 1.f / (1.f + __expf(-v.z));
    v.w = 1.f / (1.f + __expf(-v.w));
    *p = v;
}

extern "C" void kernel_launch(void* const* d_in, const int* in_sizes, int n_in,
                              void* d_out, int out_size, void* d_ws, size_t ws_size,
                              hipStream_t stream)
{
    const float* embeddings = (const float*)d_in[0];
    const int*   head_idx   = (const int*)d_in[1];
    const float* head_e     = (const float*)d_in[2];
    const int*   tail_idx   = (const int*)d_in[3];
    const float* tail_e     = (const float*)d_in[4];
    const int*   adj_rows   = (const int*)d_in[5];
    const int*   adj_cols   = (const int*)d_in[6];
    const float* adj_vals   = (const float*)d_in[7];
    const float* rel_k      = (const float*)d_in[8];
    const float* self_k     = (const float*)d_in[9];
    float* out = (float*)d_out;

    // workspace layout (total ~52.9 MB)
    char* ws = (char*)d_ws;
    float* T        = (float*)(ws);                            // 25,600,000 B
    int*   count    = (int*)  (ws + 25600000);                 //  1,600,000 B
    int*   ovf_cnt  = (int*)  (ws + 27200000);                 //          4 B
    int*   ovf_list = ovf_cnt + 1;                             //    131,072 B
    int*   buckets  = (int*)  (ws + 27331200);                 // 25,600,000 B

    // zero count + ovf_cnt (contiguous)
    hipMemsetAsync(count, 0, (size_t)RR * NN * 4 + 4, stream);

    fill_buckets<<<(RR * EE + 255) / 256, 256, 0, stream>>>(
        adj_rows, count, buckets, ovf_cnt, ovf_list);

    // self term writes logits into d_out: [head_e; tail_e] @ self_kernel
    gemm128<true><<<(2 * BB) / 64, 256, 0, stream>>>(
        head_e, tail_e, BB, self_k, out, 2 * BB);

    for (int r = 0; r < RR; r++) {
        gemm128<false><<<(NN + 63) / 64, 256, 0, stream>>>(
            embeddings, nullptr, 0, rel_k + (size_t)r * DD * OO, T, NN);
        gather_accum<<<(2 * BB * 32) / 256, 256, 0, stream>>>(
            head_idx, tail_idx, count, buckets, adj_cols, adj_vals, T, out, r);
        ovf_fix<<<32, 256, 0, stream>>>(
            ovf_cnt, ovf_list, adj_rows, adj_cols, adj_vals,
            head_idx, tail_idx, T, out, r);
    }

    sigmoid_inplace<<<(2 * BB * OO / 4) / 256, 256, 0, stream>>>(out);
}

// Round 2
// 213.419 us; speedup vs baseline: 2.2651x; 2.2651x over previous
//
#include <hip/hip_runtime.h>
#include <hip/hip_fp16.h>
#include <math.h>

#define NN 50000
#define RR 8
#define EE 100000
#define BB 16384
#define DD 128
#define OO 128
#define NKEY (RR*NN)      // 400000 (relation, node) keys
#define NT 391            // ceil(50000/128) T-GEMM blocks
#define NS 256            // 32768/128 self-GEMM blocks
#define GB (NT+NS)        // 647 GEMM-role blocks

typedef unsigned int uint;
typedef __attribute__((ext_vector_type(4))) float f32x4;
typedef __attribute__((ext_vector_type(8))) short s16x8;

__device__ inline unsigned short f2bf(float x) {
    uint u = __float_as_uint(x);
    u += 0x7FFFu + ((u >> 16) & 1u);      // round-to-nearest-even
    return (unsigned short)(u >> 16);
}
__device__ inline float bf2f(unsigned short h) {
    return __uint_as_float(((uint)h) << 16);
}

// ---------------- W transpose+split: Wt[r][prec][n][k] bf16, r=8 -> self ----------------
__global__ __launch_bounds__(256) void convert_w(
    const float* __restrict__ rel_k, const float* __restrict__ self_k,
    unsigned short* __restrict__ WtG)
{
    int r = blockIdx.x;
    const float* src = (r < RR) ? rel_k + (size_t)r * DD * OO : self_k;
    __shared__ float tt[128][133];        // [n][k], pad 133 -> conflict-free transpose
    int tid = threadIdx.x;
    for (int i = 0; i < 64; i++) {
        int idx = tid + 256 * i;          // coalesced read W[k][n]
        tt[idx & 127][idx >> 7] = src[idx];
    }
    __syncthreads();
    int n = tid >> 1, kh = (tid & 1) * 64;
    unsigned short* base = WtG + ((size_t)r * 2) * 16384;
    #pragma unroll
    for (int c = 0; c < 8; c++) {
        unsigned short hv[8], lv[8];
        #pragma unroll
        for (int q = 0; q < 8; q++) {
            float x = tt[n][kh + c * 8 + q];
            hv[q] = f2bf(x);
            lv[q] = f2bf(x - bf2f(hv[q]));
        }
        size_t off = (size_t)n * 128 + kh + c * 8;
        *(s16x8*)(base + off)          = *(s16x8*)hv;
        *(s16x8*)(base + 16384 + off)  = *(s16x8*)lv;
    }
}

// ---------------- mega: [fused bucket-build] + T_r = E@W_r (8r/block) + self-GEMM ----------------
__global__ __launch_bounds__(256, 1) void mega(
    const float* __restrict__ emb, const float* __restrict__ head_e, const float* __restrict__ tail_e,
    const int* __restrict__ adj_rows, const int* __restrict__ adj_cols, const float* __restrict__ adj_vals,
    const unsigned short* __restrict__ WtG, __half* __restrict__ T, float* __restrict__ outSelf,
    int* __restrict__ count, uint2* __restrict__ buckets,
    int rbeg, int rcnt, int cap, int doAux)
{
    __shared__ unsigned short As[2][128 * 128];   // hi/lo, swizzled [row][k]
    __shared__ unsigned short Bs[2][128 * 128];   // hi/lo, swizzled [n][k]
    const int tid = threadIdx.x;
    const int bid = blockIdx.x;

    // --- fused edge bucketing (atomics retire under the GEMM below) ---
    if (doAux) {
        for (int g = bid * 256 + tid; g < RR * EE; g += GB * 256) {
            int r = g / EE;
            int row = adj_rows[g];
            int col = adj_cols[g];
            float v = adj_vals[g];
            int key = r * NN + row;
            int pos = atomicAdd(&count[key], 1);
            if (pos < cap)
                buckets[(size_t)pos * NKEY + key] = make_uint2((uint)col, __float_as_uint(v));
        }
    }

    bool isT = bid < NT;
    const float* Asrc; int valid, rc, wslot0;
    if (isT) {
        int base = bid * 128;
        Asrc = emb + (size_t)base * DD;
        valid = NN - base; if (valid > 128) valid = 128;
        rc = rcnt; wslot0 = rbeg;
    } else {
        if (!doAux) return;
        int sb = bid - NT;
        Asrc = (sb < 128) ? head_e + (size_t)sb * 128 * DD
                          : tail_e + (size_t)(sb - 128) * 128 * DD;
        valid = 128; rc = 1; wslot0 = RR;
    }

    // --- stage A tile fp32 -> bf16 hi/lo into swizzled LDS (once, reused across r) ---
    #pragma unroll
    for (int i = 0; i < 16; i++) {
        int c = i * 256 + tid;            // 16B chunk, 32 chunks/row
        int row = c >> 5;
        int k0 = (c & 31) * 4;
        int rowc = row < valid ? row : valid - 1;
        float4 a = *(const float4*)(Asrc + (size_t)rowc * DD + k0);
        short4 h, l;
        h.x = (short)f2bf(a.x); l.x = (short)f2bf(a.x - bf2f((unsigned short)h.x));
        h.y = (short)f2bf(a.y); l.y = (short)f2bf(a.y - bf2f((unsigned short)h.y));
        h.z = (short)f2bf(a.z); l.z = (short)f2bf(a.z - bf2f((unsigned short)h.z));
        h.w = (short)f2bf(a.w); l.w = (short)f2bf(a.w - bf2f((unsigned short)h.w));
        int off = (row * 256 + k0 * 2) ^ ((row & 7) << 4);
        *(short4*)((char*)&As[0][0] + off) = h;
        *(short4*)((char*)&As[1][0] + off) = l;
    }

    // --- prefetch first W (64 KB / 256 thr = 16 x 16B) ---
    const uint4* W4 = (const uint4*)WtG;
    uint4 wpre[16];
    #pragma unroll
    for (int i = 0; i < 16; i++) wpre[i] = W4[(size_t)wslot0 * 4096 + i * 256 + tid];
    __syncthreads();

    const int l = tid & 63, w = tid >> 6;
    const int m0w = (w >> 1) * 64, n0w = (w & 1) * 64;
    const int lr = l & 15, kq = l >> 4;

    for (int rr = 0; rr < rc; rr++) {
        // write prefetched W into swizzled LDS
        #pragma unroll
        for (int i = 0; i < 16; i++) {
            int c = i * 256 + tid;
            int prec = c >> 11;
            int cc = c & 2047;
            int nn2 = cc >> 4;
            int off = (nn2 * 256 + (cc & 15) * 16) ^ ((nn2 & 7) << 4);
            *(uint4*)((char*)&Bs[prec][0] + off) = wpre[i];
        }
        __syncthreads();
        if (rr + 1 < rc) {
            #pragma unroll
            for (int i = 0; i < 16; i++)
                wpre[i] = W4[(size_t)(wslot0 + rr + 1) * 4096 + i * 256 + tid];
        }

        f32x4 acc[4][4];
        #pragma unroll
        for (int a = 0; a < 4; a++)
            #pragma unroll
            for (int b = 0; b < 4; b++)
                acc[a][b] = (f32x4){0.f, 0.f, 0.f, 0.f};

        #pragma unroll
        for (int ks = 0; ks < 4; ks++) {
            int kb = ks * 64 + kq * 16;   // byte offset of this lane's k-slice
            s16x8 ah[4], al[4], bh[4], bl[4];
            #pragma unroll
            for (int mf = 0; mf < 4; mf++) {
                int rowA = m0w + mf * 16 + lr;
                int off = (rowA * 256 + kb) ^ ((rowA & 7) << 4);
                ah[mf] = *(const s16x8*)((const char*)&As[0][0] + off);
                al[mf] = *(const s16x8*)((const char*)&As[1][0] + off);
            }
            #pragma unroll
            for (int nf = 0; nf < 4; nf++) {
                int rowB = n0w + nf * 16 + lr;
                int off = (rowB * 256 + kb) ^ ((rowB & 7) << 4);
                bh[nf] = *(const s16x8*)((const char*)&Bs[0][0] + off);
                bl[nf] = *(const s16x8*)((const char*)&Bs[1][0] + off);
            }
            #pragma unroll
            for (int mf = 0; mf < 4; mf++)
                #pragma unroll
                for (int nf = 0; nf < 4; nf++) {
                    acc[mf][nf] = __builtin_amdgcn_mfma_f32_16x16x32_bf16(ah[mf], bh[nf], acc[mf][nf], 0, 0, 0);
                    acc[mf][nf] = __builtin_amdgcn_mfma_f32_16x16x32_bf16(ah[mf], bl[nf], acc[mf][nf], 0, 0, 0);
                    acc[mf][nf] = __builtin_amdgcn_mfma_f32_16x16x32_bf16(al[mf], bh[nf], acc[mf][nf], 0, 0, 0);
                }
        }

        // epilogue: D layout col=lane&15, row=(lane>>4)*4+j  [m89-verified]
        if (isT) {
            __half* Tr = T + (size_t)rr * ((size_t)NN * DD);
            int gbase = bid * 128;
            #pragma unroll
            for (int mf = 0; mf < 4; mf++) {
                int lrow = m0w + mf * 16 + kq * 4;
                #pragma unroll
                for (int j = 0; j < 4; j++) {
                    int lr2 = lrow + j;
                    if (lr2 < valid) {
                        size_t ro = (size_t)(gbase + lr2) * OO;
                        #pragma unroll
                        for (int nf = 0; nf < 4; nf++)
                            Tr[ro + n0w + nf * 16 + lr] = __float2half(acc[mf][nf][j]);
                    }
                }
            }
        } else {
            int sb = bid - NT;
            float* Or = outSelf + (size_t)sb * 128 * OO;
            #pragma unroll
            for (int mf = 0; mf < 4; mf++) {
                int lrow = m0w + mf * 16 + kq * 4;
                #pragma unroll
                for (int j = 0; j < 4; j++) {
                    size_t ro = (size_t)(lrow + j) * OO;
                    #pragma unroll
                    for (int nf = 0; nf < 4; nf++)
                        Or[ro + n0w + nf * 16 + lr] = acc[mf][nf][j];
                }
            }
        }
        __syncthreads();
    }
}

// ---------------- gather: out[b] = sigmoid(self + sum_r sum_e v*T_r[col])  ----------------
__global__ __launch_bounds__(256) void gather(
    const int* __restrict__ head_idx, const int* __restrict__ tail_idx,
    const int* __restrict__ count, const uint2* __restrict__ buckets,
    const int* __restrict__ adj_rows, const int* __restrict__ adj_cols, const float* __restrict__ adj_vals,
    const __half* __restrict__ T, float* __restrict__ out,
    int rbeg, int rcnt, int cap, int finalize)
{
    int tid = threadIdx.x;
    int g = blockIdx.x * 256 + tid;
    int b = g >> 5;
    if (b >= 2 * BB) return;
    int lane = tid & 31;
    int half = (tid >> 5) & 1;
    int n = (b < BB) ? head_idx[b] : tail_idx[b - BB];
    float a0 = 0.f, a1 = 0.f, a2 = 0.f, a3 = 0.f;

    for (int rr = 0; rr < rcnt; rr++) {
        int r = rbeg + rr;
        int key = r * NN + n;
        int cnt = count[key];
        const char* Tr = (const char*)(T + (size_t)rr * ((size_t)NN * DD));
        if (cnt <= cap) {
            for (int j = 0; j < cnt; j++) {
                uint2 ent = buckets[(size_t)j * NKEY + key];
                float v = __uint_as_float(ent.y);
                const __half2* tp = (const __half2*)(Tr + (size_t)ent.x * 256 + lane * 8);
                float2 p0 = __half22float2(tp[0]);
                float2 p1 = __half22float2(tp[1]);
                a0 = fmaf(v, p0.x, a0); a1 = fmaf(v, p0.y, a1);
                a2 = fmaf(v, p1.x, a2); a3 = fmaf(v, p1.y, a3);
            }
        } else {
            // overflow insurance: brute ballot-scan of relation r's edges (≈never taken)
            for (int e0 = 0; e0 < EE; e0 += 32) {
                int rv = adj_rows[r * EE + e0 + lane];
                unsigned long long m = __ballot(rv == n);
                unsigned mm = (unsigned)(m >> (32 * half));
                while (mm) {
                    int bit = __builtin_ctz(mm); mm &= mm - 1;
                    int ee = e0 + bit;
                    float v = adj_vals[r * EE + ee];
                    int col = adj_cols[r * EE + ee];
                    const __half2* tp = (const __half2*)(Tr + (size_t)col * 256 + lane * 8);
                    float2 p0 = __half22float2(tp[0]);
                    float2 p1 = __half22float2(tp[1]);
                    a0 = fmaf(v, p0.x, a0); a1 = fmaf(v, p0.y, a1);
                    a2 = fmaf(v, p1.x, a2); a3 = fmaf(v, p1.y, a3);
                }
            }
        }
    }

    float4* op = (float4*)(out + (size_t)b * OO + lane * 4);
    float4 cur = *op;                 // self logits from mega
    cur.x += a0; cur.y += a1; cur.z += a2; cur.w += a3;
    if (finalize) {
        cur.x = 1.f / (1.f + __expf(-cur.x));
        cur.y = 1.f / (1.f + __expf(-cur.y));
        cur.z = 1.f / (1.f + __expf(-cur.z));
        cur.w = 1.f / (1.f + __expf(-cur.w));
    }
    *op = cur;
}

extern "C" void kernel_launch(void* const* d_in, const int* in_sizes, int n_in,
                              void* d_out, int out_size, void* d_ws, size_t ws_size,
                              hipStream_t stream)
{
    const float* embeddings = (const float*)d_in[0];
    const int*   head_idx   = (const int*)d_in[1];
    const float* head_e     = (const float*)d_in[2];
    const int*   tail_idx   = (const int*)d_in[3];
    const float* tail_e     = (const float*)d_in[4];
    const int*   adj_rows   = (const int*)d_in[5];
    const int*   adj_cols   = (const int*)d_in[6];
    const float* adj_vals   = (const float*)d_in[7];
    const float* rel_k      = (const float*)d_in[8];
    const float* self_k     = (const float*)d_in[9];
    float* out = (float*)d_out;

    char* ws = (char*)d_ws;
    int* count = (int*)ws;                                      // 1,600,000 B
    unsigned short* WtG = (unsigned short*)(ws + 1600512);      //   589,824 B
    const size_t bucketsOff = 2190848;

    size_t capB16 = (size_t)16 * NKEY * 8;                      // 51.2 MB
    size_t tAll   = (size_t)RR * NN * DD * 2;                   // 102.4 MB
    size_t tOne   = (size_t)NN * DD * 2;                        // 12.8 MB

    int mode, cap;
    if (ws_size >= bucketsOff + capB16 + tAll)      { mode = 0; cap = 16; }
    else if (ws_size >= bucketsOff + capB16 + tOne) { mode = 1; cap = 16; }
    else                                            { mode = 2; cap = 8;  }

    uint2* buckets = (uint2*)(ws + bucketsOff);
    __half* T = (__half*)(ws + bucketsOff + (size_t)cap * NKEY * 8);

    hipMemsetAsync(count, 0, (size_t)NKEY * 4, stream);
    convert_w<<<RR + 1, 256, 0, stream>>>(rel_k, self_k, WtG);

    if (mode == 0) {
        mega<<<GB, 256, 0, stream>>>(embeddings, head_e, tail_e,
                                     adj_rows, adj_cols, adj_vals,
                                     WtG, T, out, count, buckets, 0, RR, cap, 1);
        gather<<<(2 * BB * 32) / 256, 256, 0, stream>>>(head_idx, tail_idx, count, buckets,
                                                        adj_rows, adj_cols, adj_vals, T, out,
                                                        0, RR, cap, 1);
    } else {
        for (int r = 0; r < RR; r++) {
            mega<<<(r == 0 ? GB : NT), 256, 0, stream>>>(embeddings, head_e, tail_e,
                                                         adj_rows, adj_cols, adj_vals,
                                                         WtG, T, out, count, buckets,
                                                         r, 1, cap, r == 0 ? 1 : 0);
            gather<<<(2 * BB * 32) / 256, 256, 0, stream>>>(head_idx, tail_idx, count, buckets,
                                                            adj_rows, adj_cols, adj_vals, T, out,
                                                            r, 1, cap, r == 7 ? 1 : 0);
        }
    }
}

// Round 3
// 145.579 us; speedup vs baseline: 3.3206x; 1.4660x over previous
//
#include <hip/hip_runtime.h>
#include <math.h>

#define NN 50000
#define RR 8
#define EE 100000
#define BB 16384
#define NKEY 400000          // (relation, node) keys
#define ET  800000           // total edges

typedef unsigned int uint;
typedef __attribute__((ext_vector_type(4))) float f32x4;
typedef _Float16 f16x8 __attribute__((ext_vector_type(8)));
typedef _Float16 f16x4 __attribute__((ext_vector_type(4)));

// =================== prep: bucket build + emb->fp16 + W fragment prepack ===================
// grid 400 x 256. All blocks run the edge-bucket build (8 independent atomic chains/thread).
// Blocks 0..390: emb fp32->fp16. Blocks 391..399: W[r] (r=8 -> self) -> fragment-packed fp16 hi/lo.
__global__ __launch_bounds__(256) void prep(
    const float* __restrict__ emb, const float* __restrict__ rel_k, const float* __restrict__ self_k,
    const int* __restrict__ adj_rows, const int* __restrict__ adj_cols, const float* __restrict__ adj_vals,
    int* __restrict__ count, uint2* __restrict__ buckets,
    unsigned short* __restrict__ emb16, unsigned short* __restrict__ Wfrag)
{
    const int tid = threadIdx.x, bid = blockIdx.x;

    // ---- fused edge bucketing: slab[key] = 16 x (col, fp32 val), count separate ----
    {
        int g = bid * 256 + tid;                 // 102400 threads
        #pragma unroll
        for (int ii = 0; ii < 8; ii++) {
            int e = g + ii * 102400;
            if (e < ET) {
                int r = e / EE;
                int row = adj_rows[e];
                int key = r * NN + row;
                int pos = atomicAdd(&count[key], 1);
                if (pos < 16)
                    buckets[(size_t)key * 16 + pos] =
                        make_uint2((uint)adj_cols[e], __float_as_uint(adj_vals[e]));
            }
        }
    }

    if (bid < 391) {
        // ---- emb -> fp16, rows [bid*128, bid*128+128) ----
        #pragma unroll
        for (int i = 0; i < 16; i++) {
            int c = i * 256 + tid;               // 4096 float4 slots
            int row = bid * 128 + (c >> 5);
            if (row < NN) {
                int k4 = (c & 31) * 4;
                float4 v = *(const float4*)(emb + (size_t)row * 128 + k4);
                f16x4 h = { (_Float16)v.x, (_Float16)v.y, (_Float16)v.z, (_Float16)v.w };
                *(f16x4*)(emb16 + (size_t)row * 128 + k4) = h;
            }
        }
    } else {
        // ---- W prepack: Wfrag[r][plane][nfg(8)][ks(4)][lane(64)][8 fp16] ----
        int r = bid - 391;                        // 0..8 (8 = self)
        const float* src = (r < RR) ? rel_k + (size_t)r * 128 * 128 : self_k;
        __shared__ float tt[128][132];            // [n][k]
        for (int i = 0; i < 64; i++) {
            int idx = i * 256 + tid;              // coalesced read W[k][n]
            tt[idx & 127][idx >> 7] = src[idx];
        }
        __syncthreads();
        #pragma unroll
        for (int q = 0; q < 8; q++) {
            int ls = q * 256 + tid;               // 2048 lane-slots
            int nfg = ls >> 8, ks = (ls >> 6) & 3, lane = ls & 63;
            int n = nfg * 16 + (lane & 15);
            int k0 = ks * 32 + (lane >> 4) * 8;
            f16x8 hi, lo;
            #pragma unroll
            for (int j = 0; j < 8; j++) {
                float x = tt[n][k0 + j];
                _Float16 h = (_Float16)x;
                hi[j] = h;
                lo[j] = (_Float16)(x - (float)h);
            }
            size_t bo = (size_t)(r * 2) * 16384 + (size_t)(nfg * 4 + ks) * 512 + (size_t)lane * 8;
            *(f16x8*)(Wfrag + bo)         = hi;
            *(f16x8*)(Wfrag + 16384 + bo) = lo;
        }
    }
}

// =================== fused: per-block gather U_r into LDS + MFMA, all 9 terms ===================
// grid 512 x 256 (4 waves). Block tile: 64 slots x 128 out. LDS 32KB (2 fp16 planes).
__global__ __launch_bounds__(256) void fused(
    const int* __restrict__ head_idx, const int* __restrict__ tail_idx,
    const float* __restrict__ head_e, const float* __restrict__ tail_e,
    const int* __restrict__ count, const uint2* __restrict__ buckets,
    const int* __restrict__ adj_rows, const int* __restrict__ adj_cols, const float* __restrict__ adj_vals,
    const unsigned short* __restrict__ emb16, const unsigned short* __restrict__ Wfrag,
    float* __restrict__ out)
{
    __shared__ char lds[32768];                   // plane0 @0 (hi/U), plane1 @16384 (lo)
    const int tid = threadIdx.x, bid = blockIdx.x;
    const int l64 = tid & 63, w = tid >> 6;
    const int lr = l64 & 15, kq = l64 >> 4;
    const int g16 = tid >> 4, lane16 = tid & 15;

    f32x4 acc[4][2];
    #pragma unroll
    for (int a = 0; a < 4; a++)
        #pragma unroll
        for (int b = 0; b < 2; b++) acc[a][b] = (f32x4){0.f, 0.f, 0.f, 0.f};

    // ---- self term: stage 64 rows of head_e/tail_e as fp16 hi/lo ----
    #pragma unroll
    for (int i = 0; i < 8; i++) {
        int c = i * 256 + tid;                    // 2048 float4
        int rowl = c >> 5;
        int k4 = (c & 31) * 4;
        int sg = bid * 64 + rowl;
        const float* src = (sg < BB) ? head_e + (size_t)sg * 128
                                     : tail_e + (size_t)(sg - BB) * 128;
        float4 v = *(const float4*)(src + k4);
        f16x4 h, l;
        h[0] = (_Float16)v.x; l[0] = (_Float16)(v.x - (float)h[0]);
        h[1] = (_Float16)v.y; l[1] = (_Float16)(v.y - (float)h[1]);
        h[2] = (_Float16)v.z; l[2] = (_Float16)(v.z - (float)h[2]);
        h[3] = (_Float16)v.w; l[3] = (_Float16)(v.w - (float)h[3]);
        int off = (rowl * 256 + k4 * 2) ^ ((rowl & 7) << 4);
        *(f16x4*)(lds + off)         = h;
        *(f16x4*)(lds + 16384 + off) = l;
    }
    __syncthreads();
    {   // self MFMA: Ahi*Whi + Ahi*Wlo + Alo*Whi
        const unsigned short* Wb = Wfrag + (size_t)(8 * 2) * 16384;
        #pragma unroll
        for (int ks = 0; ks < 4; ks++) {
            int kb = ks * 64 + kq * 16;
            f16x8 ah[4], al[4];
            #pragma unroll
            for (int mf = 0; mf < 4; mf++) {
                int row = mf * 16 + lr;
                int off = (row * 256 + kb) ^ ((row & 7) << 4);
                ah[mf] = *(const f16x8*)(lds + off);
                al[mf] = *(const f16x8*)(lds + 16384 + off);
            }
            f16x8 bh[2], bl[2];
            #pragma unroll
            for (int nf = 0; nf < 2; nf++) {
                size_t bo = (size_t)((w * 2 + nf) * 4 + ks) * 512 + (size_t)l64 * 8;
                bh[nf] = *(const f16x8*)(Wb + bo);
                bl[nf] = *(const f16x8*)(Wb + 16384 + bo);
            }
            #pragma unroll
            for (int mf = 0; mf < 4; mf++)
                #pragma unroll
                for (int nf = 0; nf < 2; nf++) {
                    acc[mf][nf] = __builtin_amdgcn_mfma_f32_16x16x32_f16(ah[mf], bh[nf], acc[mf][nf], 0, 0, 0);
                    acc[mf][nf] = __builtin_amdgcn_mfma_f32_16x16x32_f16(ah[mf], bl[nf], acc[mf][nf], 0, 0, 0);
                    acc[mf][nf] = __builtin_amdgcn_mfma_f32_16x16x32_f16(al[mf], bh[nf], acc[mf][nf], 0, 0, 0);
                }
        }
    }
    __syncthreads();

    // ---- 8 gathered relations ----
    for (int r = 0; r < RR; r++) {
        // gather phase: 16 lanes per slot, 4 slots per group, prefetched counts/entries
        int  cnts[4]; uint2 ents[4]; int nsv[4];
        #pragma unroll
        for (int it = 0; it < 4; it++) {
            int sg = bid * 64 + it * 16 + g16;
            nsv[it] = (sg < BB) ? head_idx[sg] : tail_idx[sg - BB];
        }
        #pragma unroll
        for (int it = 0; it < 4; it++) {
            size_t key = (size_t)r * NN + nsv[it];
            cnts[it] = count[key];
            ents[it] = buckets[key * 16 + lane16];
        }
        #pragma unroll
        for (int it = 0; it < 4; it++) {
            int sl = it * 16 + g16;
            float a[8] = {0.f,0.f,0.f,0.f,0.f,0.f,0.f,0.f};
            int cnt = cnts[it];
            if (cnt <= 16) {
                for (int j = 0; j < cnt; j++) {
                    uint colw = (uint)__shfl((int)ents[it].x, j, 16);
                    float v   = __uint_as_float(__shfl((int)ents[it].y, j, 16));
                    f16x8 em = *(const f16x8*)(emb16 + (size_t)colw * 128 + lane16 * 8);
                    #pragma unroll
                    for (int q = 0; q < 8; q++) a[q] = fmaf(v, (float)em[q], a[q]);
                }
            } else {
                // overflow insurance: scan relation r (probability ~1e-4 across whole input)
                int n = nsv[it];
                for (int e0 = 0; e0 < EE; e0 += 16) {
                    int rv = adj_rows[r * EE + e0 + lane16];
                    unsigned long long m = __ballot(rv == n);
                    uint seg = (uint)((m >> (kq << 4)) & 0xFFFFull);
                    while (seg) {
                        int j = __builtin_ctz(seg); seg &= seg - 1;
                        int e = e0 + j;
                        float v = adj_vals[r * EE + e];
                        int col = adj_cols[r * EE + e];
                        f16x8 em = *(const f16x8*)(emb16 + (size_t)col * 128 + lane16 * 8);
                        #pragma unroll
                        for (int q = 0; q < 8; q++) a[q] = fmaf(v, (float)em[q], a[q]);
                    }
                }
            }
            f16x8 uu;
            #pragma unroll
            for (int q = 0; q < 8; q++) uu[q] = (_Float16)a[q];
            int off = (sl * 256 + lane16 * 16) ^ ((sl & 7) << 4);
            *(f16x8*)(lds + off) = uu;
        }
        __syncthreads();

        // MFMA phase: U * (Whi + Wlo)
        const unsigned short* Wb = Wfrag + (size_t)(r * 2) * 16384;
        #pragma unroll
        for (int ks = 0; ks < 4; ks++) {
            int kb = ks * 64 + kq * 16;
            f16x8 a[4];
            #pragma unroll
            for (int mf = 0; mf < 4; mf++) {
                int row = mf * 16 + lr;
                int off = (row * 256 + kb) ^ ((row & 7) << 4);
                a[mf] = *(const f16x8*)(lds + off);
            }
            f16x8 bh[2], bl[2];
            #pragma unroll
            for (int nf = 0; nf < 2; nf++) {
                size_t bo = (size_t)((w * 2 + nf) * 4 + ks) * 512 + (size_t)l64 * 8;
                bh[nf] = *(const f16x8*)(Wb + bo);
                bl[nf] = *(const f16x8*)(Wb + 16384 + bo);
            }
            #pragma unroll
            for (int mf = 0; mf < 4; mf++)
                #pragma unroll
                for (int nf = 0; nf < 2; nf++) {
                    acc[mf][nf] = __builtin_amdgcn_mfma_f32_16x16x32_f16(a[mf], bh[nf], acc[mf][nf], 0, 0, 0);
                    acc[mf][nf] = __builtin_amdgcn_mfma_f32_16x16x32_f16(a[mf], bl[nf], acc[mf][nf], 0, 0, 0);
                }
        }
        __syncthreads();
    }

    // ---- epilogue: sigmoid + store (D layout: col=lane&15, row=kq*4+j) ----
    #pragma unroll
    for (int mf = 0; mf < 4; mf++)
        #pragma unroll
        for (int j = 0; j < 4; j++) {
            int row = mf * 16 + kq * 4 + j;
            size_t sg = (size_t)bid * 64 + row;
            #pragma unroll
            for (int nf = 0; nf < 2; nf++) {
                int col = w * 32 + nf * 16 + lr;
                float x = acc[mf][nf][j];
                out[sg * 128 + col] = 1.f / (1.f + __expf(-x));
            }
        }
}

extern "C" void kernel_launch(void* const* d_in, const int* in_sizes, int n_in,
                              void* d_out, int out_size, void* d_ws, size_t ws_size,
                              hipStream_t stream)
{
    const float* embeddings = (const float*)d_in[0];
    const int*   head_idx   = (const int*)d_in[1];
    const float* head_e     = (const float*)d_in[2];
    const int*   tail_idx   = (const int*)d_in[3];
    const float* tail_e     = (const float*)d_in[4];
    const int*   adj_rows   = (const int*)d_in[5];
    const int*   adj_cols   = (const int*)d_in[6];
    const float* adj_vals   = (const float*)d_in[7];
    const float* rel_k      = (const float*)d_in[8];
    const float* self_k     = (const float*)d_in[9];
    float* out = (float*)d_out;

    // workspace layout (~66.2 MB)
    char* ws = (char*)d_ws;
    int*            count   = (int*)ws;                         // 1,600,000 B
    unsigned short* Wfrag   = (unsigned short*)(ws + 1600512);  //   589,824 B
    unsigned short* emb16   = (unsigned short*)(ws + 2190336);  // 12,800,000 B
    uint2*          buckets = (uint2*)(ws + 14990336);          // 51,200,000 B

    hipMemsetAsync(count, 0, (size_t)NKEY * 4, stream);

    prep<<<400, 256, 0, stream>>>(embeddings, rel_k, self_k,
                                  adj_rows, adj_cols, adj_vals,
                                  count, buckets, emb16, Wfrag);

    fused<<<512, 256, 0, stream>>>(head_idx, tail_idx, head_e, tail_e,
                                   count, buckets,
                                   adj_rows, adj_cols, adj_vals,
                                   emb16, Wfrag, out);
}

// Round 4
// 110.265 us; speedup vs baseline: 4.3841x; 1.3203x over previous
//
#include <hip/hip_runtime.h>
#include <math.h>

#define NN 50000
#define RR 8
#define EE 100000
#define BB 16384
#define ET 800000
#define LCAP 20
#define ENDV 0xFFFFFFFFu

typedef unsigned int uint;
typedef unsigned short ushort;
typedef __attribute__((ext_vector_type(4))) float f32x4;
typedef _Float16 f16x8 __attribute__((ext_vector_type(8)));
typedef _Float16 f16x4 __attribute__((ext_vector_type(4)));

// =================== prep: linked-list edge index + emb->fp16 + W fragment prepack ===================
// grid 400 x 256. All blocks: edge-pack (1 atomicExch + 1 coalesced 8B write per edge).
// Blocks 0..390: emb fp32->fp16. Blocks 391..399: W[r] (r=8 -> self) fragment prepack (hi/lo).
__global__ __launch_bounds__(256) void prep(
    const float* __restrict__ emb, const float* __restrict__ rel_k, const float* __restrict__ self_k,
    const int* __restrict__ adj_rows, const int* __restrict__ adj_cols, const float* __restrict__ adj_vals,
    uint* __restrict__ head, uint2* __restrict__ epack,
    ushort* __restrict__ emb16, ushort* __restrict__ Wfrag)
{
    const int tid = threadIdx.x, bid = blockIdx.x;

    // ---- edge pack: head[n*8+r] -> chain of edges; epack[e] = {col<<16 | val_fp16, next} ----
    {
        int g = bid * 256 + tid;
        #pragma unroll
        for (int ii = 0; ii < 8; ii++) {
            int e = g + ii * 102400;
            if (e < ET) {
                int r = e / EE;
                int row = adj_rows[e];
                uint col = (uint)adj_cols[e];
                float v = adj_vals[e];
                ushort v16 = __builtin_bit_cast(ushort, (_Float16)v);
                uint old = atomicExch(&head[row * 8 + r], (uint)e);
                epack[e] = make_uint2((col << 16) | (uint)v16, old);
            }
        }
    }

    if (bid < 391) {
        // ---- emb -> fp16, rows [bid*128, bid*128+128) ----
        #pragma unroll
        for (int i = 0; i < 16; i++) {
            int c = i * 256 + tid;
            int row = bid * 128 + (c >> 5);
            if (row < NN) {
                int k4 = (c & 31) * 4;
                float4 v = *(const float4*)(emb + (size_t)row * 128 + k4);
                f16x4 h = { (_Float16)v.x, (_Float16)v.y, (_Float16)v.z, (_Float16)v.w };
                *(f16x4*)(emb16 + (size_t)row * 128 + k4) = h;
            }
        }
    } else {
        // ---- W prepack: Wfrag[r][plane][nfg(8)][ks(4)][lane(64)][8 fp16] ----
        int r = bid - 391;                        // 0..8 (8 = self)
        const float* src = (r < RR) ? rel_k + (size_t)r * 128 * 128 : self_k;
        __shared__ float tt[128][132];            // [n][k]
        for (int i = 0; i < 64; i++) {
            int idx = i * 256 + tid;              // coalesced read W[k][n]
            tt[idx & 127][idx >> 7] = src[idx];
        }
        __syncthreads();
        #pragma unroll
        for (int q = 0; q < 8; q++) {
            int ls = q * 256 + tid;
            int nfg = ls >> 8, ks = (ls >> 6) & 3, lane = ls & 63;
            int n = nfg * 16 + (lane & 15);
            int k0 = ks * 32 + (lane >> 4) * 8;
            f16x8 hi, lo;
            #pragma unroll
            for (int j = 0; j < 8; j++) {
                float x = tt[n][k0 + j];
                _Float16 h = (_Float16)x;
                hi[j] = h;
                lo[j] = (_Float16)(x - (float)h);
            }
            size_t bo = (size_t)(r * 2) * 16384 + (size_t)(nfg * 4 + ks) * 512 + (size_t)lane * 8;
            *(f16x8*)(Wfrag + bo)         = hi;
            *(f16x8*)(Wfrag + 16384 + bo) = lo;
        }
    }
}

// =================== fused: chain traversal -> LDS lists -> gather+MFMA, all 9 terms ===================
// grid 1024 x 256 (4 waves). Block tile: 32 slots x 128 out.
__global__ __launch_bounds__(256, 4) void fused(
    const int* __restrict__ head_idx, const int* __restrict__ tail_idx,
    const float* __restrict__ head_e, const float* __restrict__ tail_e,
    const uint* __restrict__ head, const uint2* __restrict__ epack,
    const int* __restrict__ adj_rows,
    const ushort* __restrict__ emb16, const ushort* __restrict__ Wfrag,
    float* __restrict__ out)
{
    __shared__ uint lists[256 * LCAP];            // 20 KB: per-chain (col<<16|val16) entries
    __shared__ int  cnts[256];
    __shared__ char ldsB[16384];                  // self hi/lo planes, then U ping-pong planes
    const int tid = threadIdx.x, bid = blockIdx.x;
    const int l64 = tid & 63, w = tid >> 6;
    const int lr = l64 & 15, kq = l64 >> 4;
    const int g16 = tid >> 4, lane16 = tid & 15;

    // ---- issue chain head loads early: chain tid = rT*32 + slotT ----
    int slotT = tid & 31, rT = tid >> 5;
    int sgT = bid * 32 + slotT;
    int nT = (sgT < BB) ? head_idx[sgT] : tail_idx[sgT - BB];
    uint e = head[nT * 8 + rT];

    // ---- self staging: 32 rows fp32 -> fp16 hi/lo (planes at 0 and 8192) ----
    #pragma unroll
    for (int i = 0; i < 4; i++) {
        int c = i * 256 + tid;                    // 1024 float4
        int rowl = c >> 5;
        int k4 = (c & 31) * 4;
        int sg = bid * 32 + rowl;
        const float* src = (sg < BB) ? head_e + (size_t)sg * 128
                                     : tail_e + (size_t)(sg - BB) * 128;
        float4 v = *(const float4*)(src + k4);
        f16x4 h, l;
        h[0] = (_Float16)v.x; l[0] = (_Float16)(v.x - (float)h[0]);
        h[1] = (_Float16)v.y; l[1] = (_Float16)(v.y - (float)h[1]);
        h[2] = (_Float16)v.z; l[2] = (_Float16)(v.z - (float)h[2]);
        h[3] = (_Float16)v.w; l[3] = (_Float16)(v.w - (float)h[3]);
        int off = (rowl * 256 + k4 * 2) ^ ((rowl & 7) << 4);
        *(f16x4*)(ldsB + off)        = h;
        *(f16x4*)(ldsB + 8192 + off) = l;
    }

    // ---- traverse chain into LDS list (avg 2 hops, 1 chain/thread) ----
    {
        int cnt = 0;
        while (e != ENDV && cnt < LCAP) {
            uint2 p = epack[e];
            lists[tid * LCAP + cnt] = p.x;
            cnt++;
            e = p.y;
        }
        cnts[tid] = (e == ENDV) ? cnt : -1;       // -1 => brute fallback (P~1e-13)
    }
    __syncthreads();

    f32x4 acc[2][2];
    #pragma unroll
    for (int a = 0; a < 2; a++)
        #pragma unroll
        for (int b = 0; b < 2; b++) acc[a][b] = (f32x4){0.f, 0.f, 0.f, 0.f};

    // ---- self MFMA: Ahi*Whi + Ahi*Wlo + Alo*Whi ----
    {
        const ushort* Wb = Wfrag + (size_t)(8 * 2) * 16384;
        #pragma unroll
        for (int ks = 0; ks < 4; ks++) {
            int kb = ks * 64 + kq * 16;
            f16x8 ah[2], al[2], bh[2], bl[2];
            #pragma unroll
            for (int mf = 0; mf < 2; mf++) {
                int row = mf * 16 + lr;
                int off = (row * 256 + kb) ^ ((row & 7) << 4);
                ah[mf] = *(const f16x8*)(ldsB + off);
                al[mf] = *(const f16x8*)(ldsB + 8192 + off);
            }
            #pragma unroll
            for (int nf = 0; nf < 2; nf++) {
                size_t bo = (size_t)((w * 2 + nf) * 4 + ks) * 512 + (size_t)l64 * 8;
                bh[nf] = *(const f16x8*)(Wb + bo);
                bl[nf] = *(const f16x8*)(Wb + 16384 + bo);
            }
            #pragma unroll
            for (int mf = 0; mf < 2; mf++)
                #pragma unroll
                for (int nf = 0; nf < 2; nf++) {
                    acc[mf][nf] = __builtin_amdgcn_mfma_f32_16x16x32_f16(ah[mf], bh[nf], acc[mf][nf], 0, 0, 0);
                    acc[mf][nf] = __builtin_amdgcn_mfma_f32_16x16x32_f16(ah[mf], bl[nf], acc[mf][nf], 0, 0, 0);
                    acc[mf][nf] = __builtin_amdgcn_mfma_f32_16x16x32_f16(al[mf], bh[nf], acc[mf][nf], 0, 0, 0);
                }
        }
    }
    __syncthreads();   // before reusing ldsB as U planes

    // ---- 8 relations: gather U into ping-pong plane, one barrier per relation ----
    for (int r = 0; r < RR; r++) {
        char* Up = ldsB + (r & 1) * 8192;
        #pragma unroll
        for (int it = 0; it < 2; it++) {
            int slot = it * 16 + g16;
            int chain = r * 32 + slot;
            int cnt = cnts[chain];
            float a[8] = {0.f,0.f,0.f,0.f,0.f,0.f,0.f,0.f};
            if (cnt >= 0) {
                for (int j = 0; j < cnt; j++) {
                    uint pw = lists[chain * LCAP + j];          // LDS broadcast
                    float v = (float)__builtin_bit_cast(_Float16, (ushort)(pw & 0xFFFFu));
                    uint col = pw >> 16;
                    f16x8 em = *(const f16x8*)(emb16 + (size_t)col * 128 + lane16 * 8);
                    #pragma unroll
                    for (int q = 0; q < 8; q++) a[q] = fmaf(v, (float)em[q], a[q]);
                }
            } else {
                // brute fallback: scan relation r's rows (never taken in practice)
                int sg = bid * 32 + slot;
                int n = (sg < BB) ? head_idx[sg] : tail_idx[sg - BB];
                for (int e0 = 0; e0 < EE; e0 += 16) {
                    int rv = adj_rows[r * EE + e0 + lane16];
                    unsigned long long m = __ballot(rv == n);
                    uint seg = (uint)((m >> (kq << 4)) & 0xFFFFull);
                    while (seg) {
                        int j = __builtin_ctz(seg); seg &= seg - 1;
                        int ee = e0 + j;
                        uint2 p = epack[ee];
                        float v = (float)__builtin_bit_cast(_Float16, (ushort)(p.x & 0xFFFFu));
                        uint col = p.x >> 16;
                        f16x8 em = *(const f16x8*)(emb16 + (size_t)col * 128 + lane16 * 8);
                        #pragma unroll
                        for (int q = 0; q < 8; q++) a[q] = fmaf(v, (float)em[q], a[q]);
                    }
                }
            }
            f16x8 uu;
            #pragma unroll
            for (int q = 0; q < 8; q++) uu[q] = (_Float16)a[q];
            int off = (slot * 256 + lane16 * 16) ^ ((slot & 7) << 4);
            *(f16x8*)(Up + off) = uu;
        }
        __syncthreads();

        const ushort* Wb = Wfrag + (size_t)(r * 2) * 16384;
        #pragma unroll
        for (int ks = 0; ks < 4; ks++) {
            int kb = ks * 64 + kq * 16;
            f16x8 av[2], bh[2], bl[2];
            #pragma unroll
            for (int mf = 0; mf < 2; mf++) {
                int row = mf * 16 + lr;
                int off = (row * 256 + kb) ^ ((row & 7) << 4);
                av[mf] = *(const f16x8*)(Up + off);
            }
            #pragma unroll
            for (int nf = 0; nf < 2; nf++) {
                size_t bo = (size_t)((w * 2 + nf) * 4 + ks) * 512 + (size_t)l64 * 8;
                bh[nf] = *(const f16x8*)(Wb + bo);
                bl[nf] = *(const f16x8*)(Wb + 16384 + bo);
            }
            #pragma unroll
            for (int mf = 0; mf < 2; mf++)
                #pragma unroll
                for (int nf = 0; nf < 2; nf++) {
                    acc[mf][nf] = __builtin_amdgcn_mfma_f32_16x16x32_f16(av[mf], bh[nf], acc[mf][nf], 0, 0, 0);
                    acc[mf][nf] = __builtin_amdgcn_mfma_f32_16x16x32_f16(av[mf], bl[nf], acc[mf][nf], 0, 0, 0);
                }
        }
        // no trailing barrier: next iteration writes the other plane (ping-pong safe)
    }

    // ---- epilogue: sigmoid + store (D layout: col=lane&15, row=(lane>>4)*4+j) ----
    #pragma unroll
    for (int mf = 0; mf < 2; mf++)
        #pragma unroll
        for (int j = 0; j < 4; j++) {
            int row = mf * 16 + kq * 4 + j;
            size_t sg = (size_t)bid * 32 + row;
            #pragma unroll
            for (int nf = 0; nf < 2; nf++) {
                int col = w * 32 + nf * 16 + lr;
                float x = acc[mf][nf][j];
                out[sg * 128 + col] = 1.f / (1.f + __expf(-x));
            }
        }
}

extern "C" void kernel_launch(void* const* d_in, const int* in_sizes, int n_in,
                              void* d_out, int out_size, void* d_ws, size_t ws_size,
                              hipStream_t stream)
{
    const float* embeddings = (const float*)d_in[0];
    const int*   head_idx   = (const int*)d_in[1];
    const float* head_e     = (const float*)d_in[2];
    const int*   tail_idx   = (const int*)d_in[3];
    const float* tail_e     = (const float*)d_in[4];
    const int*   adj_rows   = (const int*)d_in[5];
    const int*   adj_cols   = (const int*)d_in[6];
    const float* adj_vals   = (const float*)d_in[7];
    const float* rel_k      = (const float*)d_in[8];
    const float* self_k     = (const float*)d_in[9];
    float* out = (float*)d_out;

    // workspace layout (~21.4 MB)
    char* ws = (char*)d_ws;
    uint*   head  = (uint*)ws;                        // 1,600,000 B (key = n*8 + r)
    ushort* Wfrag = (ushort*)(ws + 1600512);          //   589,824 B
    ushort* emb16 = (ushort*)(ws + 2190336);          // 12,800,000 B
    uint2*  epack = (uint2*)(ws + 14990336);          //  6,400,000 B

    hipMemsetAsync(head, 0xFF, (size_t)NN * 8 * 4, stream);

    prep<<<400, 256, 0, stream>>>(embeddings, rel_k, self_k,
                                  adj_rows, adj_cols, adj_vals,
                                  head, epack, emb16, Wfrag);

    fused<<<1024, 256, 0, stream>>>(head_idx, tail_idx, head_e, tail_e,
                                    head, epack, adj_rows,
                                    emb16, Wfrag, out);
}